// Round 9
// baseline (68.067 us; speedup 1.0000x reference)
//
#include <hip/hip_runtime.h>
#include <hip/hip_bf16.h>

#define NN 8192
#define KK 256
#define HN 4096
#define TM 256
#define TN 128
#define BK 64
#define NBLK 1056  // lower-triangle 256x128 tiles: 8*132, bijective XCD swizzle

typedef __attribute__((ext_vector_type(8))) short bf16x8;
typedef __attribute__((ext_vector_type(4))) float f32x4;

__device__ __forceinline__ void gload_lds16(const void* g, void* l) {
  __builtin_amdgcn_global_load_lds(
      (const __attribute__((address_space(1))) unsigned int*)g,
      (__attribute__((address_space(3))) unsigned int*)l, 16, 0, 0);
}

// ---- Kernel 1: row-normalize z (f32) -> zn (bf16); block 0 zeroes out ----
__global__ void nrm_kernel(const float* __restrict__ z,
                           unsigned short* __restrict__ zn,
                           float* __restrict__ out) {
  if (blockIdx.x == 0 && threadIdx.x == 0) out[0] = 0.0f;
  int row = (blockIdx.x << 2) + (threadIdx.x >> 6);
  int lane = threadIdx.x & 63;
  float4 v = ((const float4*)(z + (size_t)row * KK))[lane];
  float ss = v.x * v.x + v.y * v.y + v.z * v.z + v.w * v.w;
#pragma unroll
  for (int off = 32; off; off >>= 1) ss += __shfl_xor(ss, off, 64);
  float scale = 1.0f / fmaxf(sqrtf(ss), 1e-8f);
  union {
    __hip_bfloat16 h[4];
    ushort4 u;
  } cv;
  cv.h[0] = __float2bfloat16(v.x * scale);
  cv.h[1] = __float2bfloat16(v.y * scale);
  cv.h[2] = __float2bfloat16(v.z * scale);
  cv.h[3] = __float2bfloat16(v.w * scale);
  ((ushort4*)zn)[(size_t)row * 64 + lane] = cv.u;
}

// ---- Kernel 2: symmetric Gram-GEMM, 256x128 lower-triangle tiles ----
// R3-proven K-loop (single-buffer 48 KB LDS) at 3 blocks/CU; R5-proven
// no-barrier private-slot epilogue. p = exp(10*s_ij-10) for j<i credited to
// rowpartT[2bn+wc][row] and colpartT[2bm+wr][col]. No atomics.
__global__ __launch_bounds__(256, 3) void gemm_kernel(
    const unsigned short* __restrict__ zn, float* __restrict__ rowpartT,
    float* __restrict__ colpartT, float* __restrict__ pos) {
  __shared__ short As[TM * BK];  // 32 KiB, XOR-swizzled 16B groups
  __shared__ short Bs[TN * BK];  // 16 KiB

  const int t = threadIdx.x;
  // XCD-aware bijective swizzle (1056 = 8*132), then lower-tri decode
  int id = ((int)blockIdx.x & 7) * 132 + ((int)blockIdx.x >> 3);
  int bm = (int)((sqrtf((float)(4 * id + 1)) - 1.0f) * 0.5f);
  while (bm * (bm + 1) > id) --bm;
  while ((bm + 1) * (bm + 2) <= id) ++bm;
  const int bn = id - bm * (bm + 1);  // 0 .. 2*bm+1

  const int l = t & 63;
  const int w = t >> 6;   // 0..3
  const int wr = w >> 1;  // 0..1 : 128-row half
  const int wc = w & 1;   // 0..1 : 64-col half

  f32x4 acc[8][4];
  const f32x4 vzero = {0.f, 0.f, 0.f, 0.f};
#pragma unroll
  for (int mi = 0; mi < 8; ++mi)
#pragma unroll
    for (int ni = 0; ni < 4; ++ni) acc[mi][ni] = vzero;

  const char* zb = (const char*)zn;
  const int rloc = t >> 3;                // 0..31
  const int gsrc = (t & 7) ^ (rloc & 7);  // pre-swizzled source 16B-group
  const char* aG = zb + (size_t)(bm * TM + rloc) * 512 + gsrc * 16;
  const char* bG = zb + (size_t)(bn * TN + rloc) * 512 + gsrc * 16;

#pragma unroll
  for (int kt = 0; kt < KK / BK; ++kt) {
    if (kt) __syncthreads();  // previous tile fully consumed
#pragma unroll
    for (int ro = 0; ro < 8; ++ro)  // A: 256 rows
      gload_lds16(aG + (size_t)ro * (32 * 512) + kt * 128,
                  (char*)As + ro * 4096 + t * 16);
#pragma unroll
    for (int ro = 0; ro < 4; ++ro)  // B: 128 rows
      gload_lds16(bG + (size_t)ro * (32 * 512) + kt * 128,
                  (char*)Bs + ro * 4096 + t * 16);
    asm volatile("s_waitcnt vmcnt(0)" ::: "memory");
    __syncthreads();

#pragma unroll
    for (int kk = 0; kk < 2; ++kk) {
      bf16x8 af[8], bfr[4];
      int g = kk * 4 + (l >> 4);
#pragma unroll
      for (int mi = 0; mi < 8; ++mi) {
        int r = wr * 128 + mi * 16 + (l & 15);
        af[mi] = *(const bf16x8*)(As + r * 64 + ((g ^ (r & 7)) << 3));
      }
#pragma unroll
      for (int ni = 0; ni < 4; ++ni) {
        int r = wc * 64 + ni * 16 + (l & 15);
        bfr[ni] = *(const bf16x8*)(Bs + r * 64 + ((g ^ (r & 7)) << 3));
      }
#pragma unroll
      for (int mi = 0; mi < 8; ++mi)
#pragma unroll
        for (int ni = 0; ni < 4; ++ni)
          acc[mi][ni] = __builtin_amdgcn_mfma_f32_16x16x32_bf16(
              af[mi], bfr[ni], acc[mi][ni], 0, 0, 0);
    }
  }

  // ---- epilogue: p = exp(10s-10) for gc<gr only; private partial slots ----
  const int g16 = l >> 4;
  const int rowBase = bm * TM + wr * 128 + (g16 << 2);
  const int colBase = bn * TN + wc * 64 + (l & 15);
  const float C1 = 14.4269504088896340736f;  // 10*log2(e)
  float rs[8][4];
  float cs[4] = {0.f, 0.f, 0.f, 0.f};
#pragma unroll
  for (int mi = 0; mi < 8; ++mi) {
#pragma unroll
    for (int j = 0; j < 4; ++j) rs[mi][j] = 0.f;
#pragma unroll
    for (int ni = 0; ni < 4; ++ni) {
#pragma unroll
      for (int j = 0; j < 4; ++j) {
        int gr = rowBase + mi * 16 + j;
        int gc = colBase + ni * 16;
        float a = acc[mi][ni][j];
        if (gc == (gr ^ HN)) {  // strictly-lower hit: write both directions
          pos[gr] = a * 10.0f;
          pos[gc] = a * 10.0f;
        }
        float p = (gc < gr) ? exp2f(fmaf(a, C1, -C1)) : 0.0f;
        rs[mi][j] += p;
        cs[ni] += p;
      }
    }
  }
#pragma unroll
  for (int mi = 0; mi < 8; ++mi)
#pragma unroll
    for (int j = 0; j < 4; ++j) {
      float v = rs[mi][j];
      v += __shfl_xor(v, 1, 64);
      v += __shfl_xor(v, 2, 64);
      v += __shfl_xor(v, 4, 64);
      v += __shfl_xor(v, 8, 64);
      rs[mi][j] = v;  // valid in lanes with (l&15)==0
    }
#pragma unroll
  for (int ni = 0; ni < 4; ++ni) {
    float v = cs[ni];
    v += __shfl_xor(v, 16, 64);
    v += __shfl_xor(v, 32, 64);
    cs[ni] = v;  // valid in lanes l<16
  }
  // private-slot stores: one writer per slot element, no merge needed
  if ((l & 15) == 0) {
    float* dst = rowpartT + (size_t)(2 * bn + wc) * NN;
#pragma unroll
    for (int mi = 0; mi < 8; ++mi) {
      float4 v4 = make_float4(rs[mi][0], rs[mi][1], rs[mi][2], rs[mi][3]);
      *(float4*)(dst + rowBase + mi * 16) = v4;
    }
  }
  if (l < 16) {
    float* dst = colpartT + (size_t)(2 * bm + wr) * NN;
#pragma unroll
    for (int ni = 0; ni < 4; ++ni) dst[colBase + ni * 16] = cs[ni];
  }
}

// ---- Kernel 3: loss = mean(10 + ln(rowsum_i) - pos_i) ----
__global__ void finalize_kernel(const float* __restrict__ rowpartT,
                                const float* __restrict__ colpartT,
                                const float* __restrict__ pos,
                                float* __restrict__ out) {
  int i = blockIdx.x * 256 + threadIdx.x;  // one row per thread
  int bm = i >> 8, cn = i >> 7;
  float sum = 0.f;
  // row slots: 2bn+wc for bn=0..2bm+1 -> k in [0, 4bm+4)
#pragma unroll 4
  for (int k = 0; k < 4 * bm + 4; ++k) sum += rowpartT[(size_t)k * NN + i];
  // col slots: 2s+wr for s=(cn>>1)..31 -> k in [cn&~1, 64)
#pragma unroll 4
  for (int k = (cn & ~1); k < 64; ++k) sum += colpartT[(size_t)k * NN + i];
  float acc = 10.0f + logf(sum) - pos[i];
#pragma unroll
  for (int off = 32; off; off >>= 1) acc += __shfl_xor(acc, off, 64);
  __shared__ float ws[4];
  if ((threadIdx.x & 63) == 0) ws[threadIdx.x >> 6] = acc;
  __syncthreads();
  if (threadIdx.x == 0)
    atomicAdd(out, (ws[0] + ws[1] + ws[2] + ws[3]) * (1.0f / (float)NN));
}

extern "C" void kernel_launch(void* const* d_in, const int* in_sizes, int n_in,
                              void* d_out, int out_size, void* d_ws,
                              size_t ws_size, hipStream_t stream) {
  const float* z = (const float*)d_in[0];
  float* out = (float*)d_out;
  char* ws = (char*)d_ws;
  unsigned short* zn = (unsigned short*)ws;    // 4 MiB bf16
  float* rowpartT = (float*)(ws + (4 << 20));  // 4 MiB [128][8192]
  float* colpartT = (float*)(ws + (8 << 20));  // 2 MiB [64][8192]
  float* pos = (float*)(ws + (10 << 20));      // 32 KiB

  nrm_kernel<<<NN / 4, 256, 0, stream>>>(z, zn, out);
  gemm_kernel<<<NBLK, 256, 0, stream>>>(zn, rowpartT, colpartT, pos);
  finalize_kernel<<<NN / 256, 256, 0, stream>>>(rowpartT, colpartT, pos, out);
}

// Round 10
// 59.167 us; speedup vs baseline: 1.1504x; 1.1504x over previous
//
#include <hip/hip_runtime.h>
#include <hip/hip_bf16.h>

#define NN 8192
#define KK 256
#define HN 4096
#define TM 256
#define TN 128
#define BK 32
#define NBLK 1056  // lower-triangle 256x128 tiles: 8*132, bijective XCD swizzle

typedef __attribute__((ext_vector_type(8))) short bf16x8;
typedef __attribute__((ext_vector_type(4))) float f32x4;

__device__ __forceinline__ void gload_lds16(const void* g, void* l) {
  __builtin_amdgcn_global_load_lds(
      (const __attribute__((address_space(1))) unsigned int*)g,
      (__attribute__((address_space(3))) unsigned int*)l, 16, 0, 0);
}

// ---- Kernel 1: row-normalize z (f32) -> zn (bf16); block 0 zeroes out ----
__global__ void nrm_kernel(const float* __restrict__ z,
                           unsigned short* __restrict__ zn,
                           float* __restrict__ out) {
  if (blockIdx.x == 0 && threadIdx.x == 0) out[0] = 0.0f;
  int row = (blockIdx.x << 2) + (threadIdx.x >> 6);
  int lane = threadIdx.x & 63;
  float4 v = ((const float4*)(z + (size_t)row * KK))[lane];
  float ss = v.x * v.x + v.y * v.y + v.z * v.z + v.w * v.w;
#pragma unroll
  for (int off = 32; off; off >>= 1) ss += __shfl_xor(ss, off, 64);
  float scale = 1.0f / fmaxf(sqrtf(ss), 1e-8f);
  union {
    __hip_bfloat16 h[4];
    ushort4 u;
  } cv;
  cv.h[0] = __float2bfloat16(v.x * scale);
  cv.h[1] = __float2bfloat16(v.y * scale);
  cv.h[2] = __float2bfloat16(v.z * scale);
  cv.h[3] = __float2bfloat16(v.w * scale);
  ((ushort4*)zn)[(size_t)row * 64 + lane] = cv.u;
}

// ---- Kernel 2: symmetric Gram-GEMM, 256x128 lower-triangle tiles ----
// BK=32, 8 K-steps, double-buffered LDS (48 KB total), counted vmcnt(6):
// each step issues the next stage (6 gload_lds) and waits only for the
// CURRENT buffer (own-wave vmcnt before barrier), keeping 6 loads in
// flight across the barrier. Epilogue = R4's verified LDS-merge version.
__global__ __launch_bounds__(256, 2) void gemm_kernel(
    const unsigned short* __restrict__ zn, float* __restrict__ rowpartT,
    float* __restrict__ colpartT, float* __restrict__ pos) {
  __shared__ short As[2][TM * BK];  // 2 x 16 KiB, XOR-swizzled 16B groups
  __shared__ short Bs[2][TN * BK];  // 2 x 8 KiB

  const int t = threadIdx.x;
  // XCD-aware bijective swizzle (1056 = 8*132), then lower-tri decode
  int id = ((int)blockIdx.x & 7) * 132 + ((int)blockIdx.x >> 3);
  int bm = (int)((sqrtf((float)(4 * id + 1)) - 1.0f) * 0.5f);
  while (bm * (bm + 1) > id) --bm;
  while ((bm + 1) * (bm + 2) <= id) ++bm;
  const int bn = id - bm * (bm + 1);  // 0 .. 2*bm+1

  const int l = t & 63;
  const int w = t >> 6;   // 0..3
  const int wr = w >> 1;  // 0..1 : 128-row half
  const int wc = w & 1;   // 0..1 : 64-col half

  f32x4 acc[8][4];
  const f32x4 vzero = {0.f, 0.f, 0.f, 0.f};
#pragma unroll
  for (int mi = 0; mi < 8; ++mi)
#pragma unroll
    for (int ni = 0; ni < 4; ++ni) acc[mi][ni] = vzero;

  const char* zb = (const char*)zn;
  const int rloc = t >> 2;                // 0..63 (row within 64-row round)
  const int gsrc = (t & 3) ^ (rloc & 3);  // pre-swizzled source 16B-group
  const char* aG = zb + (size_t)(bm * TM + rloc) * 512 + gsrc * 16;
  const char* bG = zb + (size_t)(bn * TN + rloc) * 512 + gsrc * 16;

  // one K-step stage: A 256 rows (4 rounds of 64) + B 128 rows (2 rounds)
#define STAGE(buf, kt)                                                \
  do {                                                                \
    _Pragma("unroll") for (int ro = 0; ro < 4; ++ro)                  \
        gload_lds16(aG + (size_t)ro * (64 * 512) + (kt)*64,           \
                    (char*)(&As[buf][0]) + ro * 4096 + t * 16);       \
    _Pragma("unroll") for (int ro = 0; ro < 2; ++ro)                  \
        gload_lds16(bG + (size_t)ro * (64 * 512) + (kt)*64,           \
                    (char*)(&Bs[buf][0]) + ro * 4096 + t * 16);       \
  } while (0)

  STAGE(0, 0);

#pragma unroll
  for (int kt = 0; kt < KK / BK; ++kt) {
    const int cur = kt & 1;
    if (kt < KK / BK - 1) {
      STAGE(cur ^ 1, kt + 1);  // next stage: 6 loads stay in flight
      asm volatile("s_waitcnt vmcnt(6)\ns_barrier" ::: "memory");
    } else {
      asm volatile("s_waitcnt vmcnt(0)\ns_barrier" ::: "memory");
    }
    bf16x8 af[8], bfr[4];
    const int g = l >> 4;  // 0..3 : 16B k-group within 64B row
#pragma unroll
    for (int mi = 0; mi < 8; ++mi) {
      int r = wr * 128 + mi * 16 + (l & 15);
      af[mi] = *(const bf16x8*)((const char*)&As[cur][0] + r * 64 +
                                ((g ^ (r & 3)) << 4));
    }
#pragma unroll
    for (int ni = 0; ni < 4; ++ni) {
      int r = wc * 64 + ni * 16 + (l & 15);
      bfr[ni] = *(const bf16x8*)((const char*)&Bs[cur][0] + r * 64 +
                                 ((g ^ (r & 3)) << 4));
    }
    __builtin_amdgcn_s_setprio(1);
#pragma unroll
    for (int mi = 0; mi < 8; ++mi)
#pragma unroll
      for (int ni = 0; ni < 4; ++ni)
        acc[mi][ni] = __builtin_amdgcn_mfma_f32_16x16x32_bf16(
            af[mi], bfr[ni], acc[mi][ni], 0, 0, 0);
    __builtin_amdgcn_s_setprio(0);
    // own ds_reads complete before any wave stages into buf cur next iter
    asm volatile("s_waitcnt lgkmcnt(0)\ns_barrier" ::: "memory");
  }

  // ---- epilogue (R4-verified): exp(10s-10) for gc<gr; LDS-merge; single
  // writer per slot: rowpartT[row][64] (bn), colpartT[col][32] (bm) ----
  const int g16 = l >> 4;
  const int rowBase = bm * TM + wr * 128 + (g16 << 2);
  const int colBase = bn * TN + wc * 64 + (l & 15);
  const float C1 = 14.4269504088896340736f;  // 10*log2(e)
  float rs[8][4];
  float cs[4] = {0.f, 0.f, 0.f, 0.f};
#pragma unroll
  for (int mi = 0; mi < 8; ++mi) {
#pragma unroll
    for (int j = 0; j < 4; ++j) rs[mi][j] = 0.f;
#pragma unroll
    for (int ni = 0; ni < 4; ++ni) {
#pragma unroll
      for (int j = 0; j < 4; ++j) {
        int gr = rowBase + mi * 16 + j;
        int gc = colBase + ni * 16;
        float a = acc[mi][ni][j];
        if (gc == (gr ^ HN)) {  // strictly-lower hit: write both directions
          pos[gr] = a * 10.0f;
          pos[gc] = a * 10.0f;
        }
        float p = (gc < gr) ? exp2f(fmaf(a, C1, -C1)) : 0.0f;
        rs[mi][j] += p;
        cs[ni] += p;
      }
    }
  }
#pragma unroll
  for (int mi = 0; mi < 8; ++mi)
#pragma unroll
    for (int j = 0; j < 4; ++j) {
      float v = rs[mi][j];
      v += __shfl_xor(v, 1, 64);
      v += __shfl_xor(v, 2, 64);
      v += __shfl_xor(v, 4, 64);
      v += __shfl_xor(v, 8, 64);
      rs[mi][j] = v;  // valid in lanes with (l&15)==0
    }
#pragma unroll
  for (int ni = 0; ni < 4; ++ni) {
    float v = cs[ni];
    v += __shfl_xor(v, 16, 64);
    v += __shfl_xor(v, 32, 64);
    cs[ni] = v;  // valid in lanes l<16
  }

  // merge wave pairs via LDS (reuse As), then ONE writer per slot
  float* red = (float*)&As[0][0];  // [0..255]: rows, [256..383]: cols
  __syncthreads();                 // all K-loop LDS reads done
  if (wc == 1 && (l & 15) == 0) {
#pragma unroll
    for (int mi = 0; mi < 8; ++mi)
#pragma unroll
      for (int j = 0; j < 4; ++j)
        red[wr * 128 + mi * 16 + (g16 << 2) + j] = rs[mi][j];
  }
  if (wr == 1 && l < 16) {
#pragma unroll
    for (int ni = 0; ni < 4; ++ni) red[256 + wc * 64 + ni * 16 + l] = cs[ni];
  }
  __syncthreads();
  if (wc == 0 && (l & 15) == 0) {
#pragma unroll
    for (int mi = 0; mi < 8; ++mi)
#pragma unroll
      for (int j = 0; j < 4; ++j) {
        int off = mi * 16 + (g16 << 2) + j;
        rowpartT[(size_t)(bm * TM + wr * 128 + off) * 64 + bn] =
            rs[mi][j] + red[wr * 128 + off];
      }
  }
  if (wr == 0 && l < 16) {
#pragma unroll
    for (int ni = 0; ni < 4; ++ni) {
      int c = bn * TN + wc * 64 + ni * 16 + l;
      colpartT[(size_t)c * 32 + bm] = cs[ni] + red[256 + wc * 64 + ni * 16 + l];
    }
  }
}

// ---- Kernel 3: loss = mean(10 + ln(rowsum_i) - pos_i), rowsum from partials
__global__ void finalize_kernel(const float* __restrict__ rowpartT,
                                const float* __restrict__ colpartT,
                                const float* __restrict__ pos,
                                float* __restrict__ out) {
  int i = blockIdx.x * 256 + threadIdx.x;  // one row per thread
  int bm = i >> 8, cn = i >> 7;
  float s = 0.f;
  const float* rp = rowpartT + (size_t)i * 64;
  int nr = 2 * bm + 2;  // always even
  for (int k = 0; k < nr; k += 2) {
    float2 v = *(const float2*)(rp + k);
    s += v.x + v.y;
  }
  const float* cp = colpartT + (size_t)i * 32;
  for (int k = (cn >> 1); k < 32; ++k) s += cp[k];
  float acc = 10.0f + logf(s) - pos[i];
#pragma unroll
  for (int off = 32; off; off >>= 1) acc += __shfl_xor(acc, off, 64);
  __shared__ float ws[4];
  if ((threadIdx.x & 63) == 0) ws[threadIdx.x >> 6] = acc;
  __syncthreads();
  if (threadIdx.x == 0)
    atomicAdd(out, (ws[0] + ws[1] + ws[2] + ws[3]) * (1.0f / (float)NN));
}

extern "C" void kernel_launch(void* const* d_in, const int* in_sizes, int n_in,
                              void* d_out, int out_size, void* d_ws,
                              size_t ws_size, hipStream_t stream) {
  const float* z = (const float*)d_in[0];
  float* out = (float*)d_out;
  char* ws = (char*)d_ws;
  unsigned short* zn = (unsigned short*)ws;    // 4 MiB bf16
  float* rowpartT = (float*)(ws + (4 << 20));  // 2 MiB [8192][64]
  float* colpartT = (float*)(ws + (6 << 20));  // 1 MiB [8192][32]
  float* pos = (float*)(ws + (7 << 20));       // 32 KiB

  nrm_kernel<<<NN / 4, 256, 0, stream>>>(z, zn, out);
  gemm_kernel<<<NBLK, 256, 0, stream>>>(zn, rowpartT, colpartT, pos);
  finalize_kernel<<<NN / 256, 256, 0, stream>>>(rowpartT, colpartT, pos, out);
}

// Round 11
// 54.631 us; speedup vs baseline: 1.2459x; 1.0830x over previous
//
#include <hip/hip_runtime.h>
#include <hip/hip_bf16.h>

#define NN 8192
#define KK 256
#define HN 4096
#define TM 256
#define TN 128
#define BK 64
#define NBLK 1056  // lower-triangle 256x128 tiles: 8*132, bijective XCD swizzle

typedef __attribute__((ext_vector_type(8))) short bf16x8;
typedef __attribute__((ext_vector_type(4))) float f32x4;

__device__ __forceinline__ void gload_lds16(const void* g, void* l) {
  __builtin_amdgcn_global_load_lds(
      (const __attribute__((address_space(1))) unsigned int*)g,
      (__attribute__((address_space(3))) unsigned int*)l, 16, 0, 0);
}

// ---- Kernel 1: row-normalize z (f32) -> zn (bf16); block 0 zeroes out ----
__global__ void nrm_kernel(const float* __restrict__ z,
                           unsigned short* __restrict__ zn,
                           float* __restrict__ out) {
  if (blockIdx.x == 0 && threadIdx.x == 0) out[0] = 0.0f;
  int row = (blockIdx.x << 2) + (threadIdx.x >> 6);
  int lane = threadIdx.x & 63;
  float4 v = ((const float4*)(z + (size_t)row * KK))[lane];
  float ss = v.x * v.x + v.y * v.y + v.z * v.z + v.w * v.w;
#pragma unroll
  for (int off = 32; off; off >>= 1) ss += __shfl_xor(ss, off, 64);
  float scale = 1.0f / fmaxf(sqrtf(ss), 1e-8f);
  union {
    __hip_bfloat16 h[4];
    ushort4 u;
  } cv;
  cv.h[0] = __float2bfloat16(v.x * scale);
  cv.h[1] = __float2bfloat16(v.y * scale);
  cv.h[2] = __float2bfloat16(v.z * scale);
  cv.h[3] = __float2bfloat16(v.w * scale);
  ((ushort4*)zn)[(size_t)row * 64 + lane] = cv.u;
}

// ---- Kernel 2: symmetric Gram-GEMM, 256x128 lower-triangle tiles ----
// 512 threads = 8 waves of 64x64 -> 4 waves/SIMD at 2 blocks/CU (same L2
// panel footprint as the 42us best, double the TLP). R4-proven single-buffer
// K-loop + XOR swizzle; R5-proven private-slot epilogue (no atomics/merge).
__global__ __launch_bounds__(512, 4) void gemm_kernel(
    const unsigned short* __restrict__ zn, float* __restrict__ rowpartT,
    float* __restrict__ colpartT, float* __restrict__ pos) {
  __shared__ short As[TM * BK];  // 32 KiB, XOR-swizzled 16B groups
  __shared__ short Bs[TN * BK];  // 16 KiB

  const int t = threadIdx.x;
  // XCD-aware bijective swizzle (1056 = 8*132), then lower-tri decode
  int id = ((int)blockIdx.x & 7) * 132 + ((int)blockIdx.x >> 3);
  int bm = (int)((sqrtf((float)(4 * id + 1)) - 1.0f) * 0.5f);
  while (bm * (bm + 1) > id) --bm;
  while ((bm + 1) * (bm + 2) <= id) ++bm;
  const int bn = id - bm * (bm + 1);  // 0 .. 2*bm+1

  const int l = t & 63;
  const int w = t >> 6;   // 0..7
  const int wr = w >> 1;  // 0..3 : 64-row band
  const int wc = w & 1;   // 0..1 : 64-col band

  f32x4 acc[4][4];
  const f32x4 vzero = {0.f, 0.f, 0.f, 0.f};
#pragma unroll
  for (int mi = 0; mi < 4; ++mi)
#pragma unroll
    for (int ni = 0; ni < 4; ++ni) acc[mi][ni] = vzero;

  const char* zb = (const char*)zn;
  const int rloc = t >> 3;                // 0..63
  const int gsrc = (t & 7) ^ (rloc & 7);  // pre-swizzled source 16B-group
  const char* aG = zb + (size_t)(bm * TM + rloc) * 512 + gsrc * 16;
  const char* bG = zb + (size_t)(bn * TN + rloc) * 512 + gsrc * 16;

#pragma unroll
  for (int kt = 0; kt < KK / BK; ++kt) {
    if (kt) __syncthreads();  // previous tile fully consumed
#pragma unroll
    for (int ro = 0; ro < 4; ++ro)  // A: 256 rows, 4 rounds of 64
      gload_lds16(aG + (size_t)ro * (64 * 512) + kt * 128,
                  (char*)As + ro * 8192 + t * 16);
#pragma unroll
    for (int ro = 0; ro < 2; ++ro)  // B: 128 rows, 2 rounds of 64
      gload_lds16(bG + (size_t)ro * (64 * 512) + kt * 128,
                  (char*)Bs + ro * 8192 + t * 16);
    asm volatile("s_waitcnt vmcnt(0)" ::: "memory");
    __syncthreads();

#pragma unroll
    for (int kk = 0; kk < 2; ++kk) {
      bf16x8 af[4], bfr[4];
      int g = kk * 4 + (l >> 4);
#pragma unroll
      for (int mi = 0; mi < 4; ++mi) {
        int r = wr * 64 + mi * 16 + (l & 15);
        af[mi] = *(const bf16x8*)(As + r * 64 + ((g ^ (r & 7)) << 3));
      }
#pragma unroll
      for (int ni = 0; ni < 4; ++ni) {
        int r = wc * 64 + ni * 16 + (l & 15);
        bfr[ni] = *(const bf16x8*)(Bs + r * 64 + ((g ^ (r & 7)) << 3));
      }
#pragma unroll
      for (int mi = 0; mi < 4; ++mi)
#pragma unroll
        for (int ni = 0; ni < 4; ++ni)
          acc[mi][ni] = __builtin_amdgcn_mfma_f32_16x16x32_bf16(
              af[mi], bfr[ni], acc[mi][ni], 0, 0, 0);
    }
  }

  // ---- epilogue: p = exp(10s-10) for gc<gr only; private partial slots ----
  const int g16 = l >> 4;
  const int rowBase = bm * TM + wr * 64 + (g16 << 2);
  const int colBase = bn * TN + wc * 64 + (l & 15);
  const float C1 = 14.4269504088896340736f;  // 10*log2(e)
  float rs[4][4];
  float cs[4] = {0.f, 0.f, 0.f, 0.f};
#pragma unroll
  for (int mi = 0; mi < 4; ++mi) {
#pragma unroll
    for (int j = 0; j < 4; ++j) rs[mi][j] = 0.f;
#pragma unroll
    for (int ni = 0; ni < 4; ++ni) {
#pragma unroll
      for (int j = 0; j < 4; ++j) {
        int gr = rowBase + mi * 16 + j;
        int gc = colBase + ni * 16;
        float a = acc[mi][ni][j];
        if (gc == (gr ^ HN)) {  // strictly-lower hit: write both directions
          pos[gr] = a * 10.0f;
          pos[gc] = a * 10.0f;
        }
        float p = (gc < gr) ? exp2f(fmaf(a, C1, -C1)) : 0.0f;
        rs[mi][j] += p;
        cs[ni] += p;
      }
    }
  }
#pragma unroll
  for (int mi = 0; mi < 4; ++mi)
#pragma unroll
    for (int j = 0; j < 4; ++j) {
      float v = rs[mi][j];
      v += __shfl_xor(v, 1, 64);
      v += __shfl_xor(v, 2, 64);
      v += __shfl_xor(v, 4, 64);
      v += __shfl_xor(v, 8, 64);
      rs[mi][j] = v;  // valid in lanes with (l&15)==0
    }
#pragma unroll
  for (int ni = 0; ni < 4; ++ni) {
    float v = cs[ni];
    v += __shfl_xor(v, 16, 64);
    v += __shfl_xor(v, 32, 64);
    cs[ni] = v;  // valid in lanes l<16
  }
  // private-slot stores: one writer per slot element, no merge needed
  if ((l & 15) == 0) {
    float* dst = rowpartT + (size_t)(2 * bn + wc) * NN;  // 128 slots
#pragma unroll
    for (int mi = 0; mi < 4; ++mi) {
      float4 v4 = make_float4(rs[mi][0], rs[mi][1], rs[mi][2], rs[mi][3]);
      *(float4*)(dst + rowBase + mi * 16) = v4;
    }
  }
  if (l < 16) {
    float* dst = colpartT + (size_t)(4 * bm + wr) * NN;  // 128 slots
#pragma unroll
    for (int ni = 0; ni < 4; ++ni) dst[colBase + ni * 16] = cs[ni];
  }
}

// ---- Kernel 3: loss = mean(10 + ln(rowsum_i) - pos_i) ----
__global__ void finalize_kernel(const float* __restrict__ rowpartT,
                                const float* __restrict__ colpartT,
                                const float* __restrict__ pos,
                                float* __restrict__ out) {
  int i = blockIdx.x * 256 + threadIdx.x;  // one row per thread
  int bm = i >> 8, cn = i >> 7;
  float sum = 0.f;
  // row slots: 2bn+wc for bn=0..2bm+1 -> k in [0, 4bm+4)
#pragma unroll 4
  for (int k = 0; k < 4 * bm + 4; ++k) sum += rowpartT[(size_t)k * NN + i];
  // col slots: 4s+wr for s=(cn>>1)..31 -> k in [4*(cn>>1), 128)
#pragma unroll 4
  for (int k = 4 * (cn >> 1); k < 128; ++k) sum += colpartT[(size_t)k * NN + i];
  float acc = 10.0f + logf(sum) - pos[i];
#pragma unroll
  for (int off = 32; off; off >>= 1) acc += __shfl_xor(acc, off, 64);
  __shared__ float ws[4];
  if ((threadIdx.x & 63) == 0) ws[threadIdx.x >> 6] = acc;
  __syncthreads();
  if (threadIdx.x == 0)
    atomicAdd(out, (ws[0] + ws[1] + ws[2] + ws[3]) * (1.0f / (float)NN));
}

extern "C" void kernel_launch(void* const* d_in, const int* in_sizes, int n_in,
                              void* d_out, int out_size, void* d_ws,
                              size_t ws_size, hipStream_t stream) {
  const float* z = (const float*)d_in[0];
  float* out = (float*)d_out;
  char* ws = (char*)d_ws;
  unsigned short* zn = (unsigned short*)ws;     // 4 MiB bf16
  float* rowpartT = (float*)(ws + (4 << 20));   // 4 MiB [128][8192]
  float* colpartT = (float*)(ws + (8 << 20));   // 4 MiB [128][8192]
  float* pos = (float*)(ws + (12 << 20));       // 32 KiB

  nrm_kernel<<<NN / 4, 256, 0, stream>>>(z, zn, out);
  gemm_kernel<<<NBLK, 512, 0, stream>>>(zn, rowpartT, colpartT, pos);
  finalize_kernel<<<NN / 256, 256, 0, stream>>>(rowpartT, colpartT, pos, out);
}

// Round 12
// 48.869 us; speedup vs baseline: 1.3928x; 1.1179x over previous
//
#include <hip/hip_runtime.h>
#include <hip/hip_bf16.h>

#define NN 8192
#define KK 256
#define HN 4096
#define TM 256
#define TN 128
#define BK 128  // fp8 bytes per LDS row (128 B rows = verified swizzle)
#define NBLK 1056  // lower-triangle 256x128 tiles: 8*132, bijective XCD swizzle

typedef __attribute__((ext_vector_type(4))) float f32x4;

__device__ __forceinline__ void gload_lds16(const void* g, void* l) {
  __builtin_amdgcn_global_load_lds(
      (const __attribute__((address_space(1))) unsigned int*)g,
      (__attribute__((address_space(3))) unsigned int*)l, 16, 0, 0);
}

// ---- Kernel 1: row-normalize z (f32) -> fp8 e4m3 zn; block 0 zeroes out ----
__global__ void nrm_kernel(const float* __restrict__ z,
                           unsigned int* __restrict__ zn,
                           float* __restrict__ out) {
  if (blockIdx.x == 0 && threadIdx.x == 0) out[0] = 0.0f;
  int row = (blockIdx.x << 2) + (threadIdx.x >> 6);
  int lane = threadIdx.x & 63;
  float4 v = ((const float4*)(z + (size_t)row * KK))[lane];
  float ss = v.x * v.x + v.y * v.y + v.z * v.z + v.w * v.w;
#pragma unroll
  for (int off = 32; off; off >>= 1) ss += __shfl_xor(ss, off, 64);
  float scale = 1.0f / fmaxf(sqrtf(ss), 1e-8f);
  int lo = __builtin_amdgcn_cvt_pk_fp8_f32(v.x * scale, v.y * scale, 0, false);
  int all = __builtin_amdgcn_cvt_pk_fp8_f32(v.z * scale, v.w * scale, lo, true);
  zn[(size_t)row * 64 + lane] = (unsigned int)all;
}

// ---- Kernel 2: symmetric Gram-GEMM (fp8), 256x128 lower-triangle tiles ----
// 512 thr / 8 waves of 64x64; single-buffer 48 KB LDS; BK=128 fp8 -> only
// 2 K-tile iterations (4 barriers vs 8), half the staging bytes/ops of bf16.
// MFMA fp8_fp8 16x16x32 = bf16 rate. Private-slot epilogue, no atomics.
__global__ __launch_bounds__(512, 4) void gemm_kernel(
    const unsigned char* __restrict__ zn, float* __restrict__ rowpartT,
    float* __restrict__ colpartT, float* __restrict__ pos) {
  __shared__ char As[TM * BK];  // 32 KiB, XOR-swizzled 16B groups
  __shared__ char Bs[TN * BK];  // 16 KiB

  const int t = threadIdx.x;
  // XCD-aware bijective swizzle (1056 = 8*132), then lower-tri decode
  int id = ((int)blockIdx.x & 7) * 132 + ((int)blockIdx.x >> 3);
  int bm = (int)((sqrtf((float)(4 * id + 1)) - 1.0f) * 0.5f);
  while (bm * (bm + 1) > id) --bm;
  while ((bm + 1) * (bm + 2) <= id) ++bm;
  const int bn = id - bm * (bm + 1);  // 0 .. 2*bm+1

  const int l = t & 63;
  const int w = t >> 6;   // 0..7
  const int wr = w >> 1;  // 0..3 : 64-row band
  const int wc = w & 1;   // 0..1 : 64-col band

  f32x4 acc[4][4];
  const f32x4 vzero = {0.f, 0.f, 0.f, 0.f};
#pragma unroll
  for (int mi = 0; mi < 4; ++mi)
#pragma unroll
    for (int ni = 0; ni < 4; ++ni) acc[mi][ni] = vzero;

  const char* zb = (const char*)zn;  // fp8 rows: 256 B
  const int rloc = t >> 3;                // 0..63 (row within 64-row round)
  const int gsrc = (t & 7) ^ (rloc & 7);  // pre-swizzled source 16B-group
  const char* aG = zb + (size_t)(bm * TM + rloc) * 256 + gsrc * 16;
  const char* bG = zb + (size_t)(bn * TN + rloc) * 256 + gsrc * 16;

#pragma unroll
  for (int kt = 0; kt < KK / BK; ++kt) {  // 2 iterations
    if (kt) __syncthreads();  // previous tile fully consumed
#pragma unroll
    for (int ro = 0; ro < 4; ++ro)  // A: 256 rows, 4 rounds of 64
      gload_lds16(aG + (size_t)ro * (64 * 256) + kt * 128,
                  (char*)As + ro * 8192 + t * 16);
#pragma unroll
    for (int ro = 0; ro < 2; ++ro)  // B: 128 rows, 2 rounds of 64
      gload_lds16(bG + (size_t)ro * (64 * 256) + kt * 128,
                  (char*)Bs + ro * 8192 + t * 16);
    asm volatile("s_waitcnt vmcnt(0)" ::: "memory");
    __syncthreads();

#pragma unroll
    for (int kk = 0; kk < 4; ++kk) {  // K=32 per MFMA, 128 per tile
      long af[4], bfr[4];
      const int g16 = kk * 2 + ((l >> 4) >> 1);  // 16B group within 128B row
      const int half = ((l >> 4) & 1) << 3;      // 8B half within the group
#pragma unroll
      for (int mi = 0; mi < 4; ++mi) {
        int r = wr * 64 + mi * 16 + (l & 15);
        af[mi] =
            *(const long*)(As + r * 128 + ((g16 ^ (r & 7)) << 4) + half);
      }
#pragma unroll
      for (int ni = 0; ni < 4; ++ni) {
        int r = wc * 64 + ni * 16 + (l & 15);
        bfr[ni] =
            *(const long*)(Bs + r * 128 + ((g16 ^ (r & 7)) << 4) + half);
      }
#pragma unroll
      for (int mi = 0; mi < 4; ++mi)
#pragma unroll
        for (int ni = 0; ni < 4; ++ni)
          acc[mi][ni] = __builtin_amdgcn_mfma_f32_16x16x32_fp8_fp8(
              af[mi], bfr[ni], acc[mi][ni], 0, 0, 0);
    }
  }

  // ---- epilogue: p = exp(10s-10) for gc<gr only; private partial slots ----
  const int e16 = l >> 4;
  const int rowBase = bm * TM + wr * 64 + (e16 << 2);
  const int colBase = bn * TN + wc * 64 + (l & 15);
  const float C1 = 14.4269504088896340736f;  // 10*log2(e)
  float rs[4][4];
  float cs[4] = {0.f, 0.f, 0.f, 0.f};
#pragma unroll
  for (int mi = 0; mi < 4; ++mi) {
#pragma unroll
    for (int j = 0; j < 4; ++j) rs[mi][j] = 0.f;
#pragma unroll
    for (int ni = 0; ni < 4; ++ni) {
#pragma unroll
      for (int j = 0; j < 4; ++j) {
        int gr = rowBase + mi * 16 + j;
        int gc = colBase + ni * 16;
        float a = acc[mi][ni][j];
        if (gc == (gr ^ HN)) {  // strictly-lower hit: write both directions
          pos[gr] = a * 10.0f;
          pos[gc] = a * 10.0f;
        }
        float p = (gc < gr) ? exp2f(fmaf(a, C1, -C1)) : 0.0f;
        rs[mi][j] += p;
        cs[ni] += p;
      }
    }
  }
#pragma unroll
  for (int mi = 0; mi < 4; ++mi)
#pragma unroll
    for (int j = 0; j < 4; ++j) {
      float v = rs[mi][j];
      v += __shfl_xor(v, 1, 64);
      v += __shfl_xor(v, 2, 64);
      v += __shfl_xor(v, 4, 64);
      v += __shfl_xor(v, 8, 64);
      rs[mi][j] = v;  // valid in lanes with (l&15)==0
    }
#pragma unroll
  for (int ni = 0; ni < 4; ++ni) {
    float v = cs[ni];
    v += __shfl_xor(v, 16, 64);
    v += __shfl_xor(v, 32, 64);
    cs[ni] = v;  // valid in lanes l<16
  }
  // private-slot stores: one writer per slot element, no merge needed
  if ((l & 15) == 0) {
    float* dst = rowpartT + (size_t)(2 * bn + wc) * NN;  // 128 slots
#pragma unroll
    for (int mi = 0; mi < 4; ++mi) {
      float4 v4 = make_float4(rs[mi][0], rs[mi][1], rs[mi][2], rs[mi][3]);
      *(float4*)(dst + rowBase + mi * 16) = v4;
    }
  }
  if (l < 16) {
    float* dst = colpartT + (size_t)(4 * bm + wr) * NN;  // 128 slots
#pragma unroll
    for (int ni = 0; ni < 4; ++ni) dst[colBase + ni * 16] = cs[ni];
  }
}

// ---- Kernel 3: loss = mean(10 + ln(rowsum_i) - pos_i) ----
__global__ void finalize_kernel(const float* __restrict__ rowpartT,
                                const float* __restrict__ colpartT,
                                const float* __restrict__ pos,
                                float* __restrict__ out) {
  int i = blockIdx.x * 256 + threadIdx.x;  // one row per thread
  int bm = i >> 8, cn = i >> 7;
  float sum = 0.f;
  // row slots: 2bn+wc for bn=0..2bm+1 -> k in [0, 4bm+4)
#pragma unroll 4
  for (int k = 0; k < 4 * bm + 4; ++k) sum += rowpartT[(size_t)k * NN + i];
  // col slots: 4s+wr for s=(cn>>1)..31 -> k in [4*(cn>>1), 128)
#pragma unroll 4
  for (int k = 4 * (cn >> 1); k < 128; ++k) sum += colpartT[(size_t)k * NN + i];
  float acc = 10.0f + logf(sum) - pos[i];
#pragma unroll
  for (int off = 32; off; off >>= 1) acc += __shfl_xor(acc, off, 64);
  __shared__ float ws[4];
  if ((threadIdx.x & 63) == 0) ws[threadIdx.x >> 6] = acc;
  __syncthreads();
  if (threadIdx.x == 0)
    atomicAdd(out, (ws[0] + ws[1] + ws[2] + ws[3]) * (1.0f / (float)NN));
}

extern "C" void kernel_launch(void* const* d_in, const int* in_sizes, int n_in,
                              void* d_out, int out_size, void* d_ws,
                              size_t ws_size, hipStream_t stream) {
  const float* z = (const float*)d_in[0];
  float* out = (float*)d_out;
  char* ws = (char*)d_ws;
  unsigned char* zn = (unsigned char*)ws;      // 2 MiB fp8
  float* rowpartT = (float*)(ws + (2 << 20));  // 4 MiB [128][8192]
  float* colpartT = (float*)(ws + (6 << 20));  // 4 MiB [128][8192]
  float* pos = (float*)(ws + (10 << 20));      // 32 KiB

  nrm_kernel<<<NN / 4, 256, 0, stream>>>(z, (unsigned int*)zn, out);
  gemm_kernel<<<NBLK, 512, 0, stream>>>(zn, rowpartT, colpartT, pos);
  finalize_kernel<<<NN / 256, 256, 0, stream>>>(rowpartT, colpartT, pos, out);
}